// Round 2
// baseline (446.524 us; speedup 1.0000x reference)
//
#include <hip/hip_runtime.h>
#include <stdint.h>

#define NB 1024
#define ND 512
#define NC 100000
#define MTILES 391       // ceil(NC/256)
#define MARGINF 0.1f

using bf16x8 = __attribute__((ext_vector_type(8))) short;
using f32x4  = __attribute__((ext_vector_type(4))) float;

// ---------- helpers ----------
__device__ __forceinline__ uint32_t f2bf(float f) {
  uint32_t u = __float_as_uint(f);
  return (u + 0x7fffu + ((u >> 16) & 1u)) >> 16;
}
__device__ __forceinline__ uint32_t pack2bf(float x, float y) {
  return f2bf(x) | (f2bf(y) << 16);
}

// ---------- kernel 1: normalize fp32 rows -> bf16 in MFMA-FRAGMENT layout ----
// Block = 256 thr, 16 rows. Output: one 16KB "frag-tile" per block; fragment
// kc (1KB) covers k in [kc*32, kc*32+32); 16B unit u = g*16 + rs holds row rs,
// k = kc*32 + g*8 .. +8 — exactly the 16x16x32 MFMA operand order, so a lane's
// fragment is at base + lane*16.
__global__ __launch_bounds__(256)
void normalize_relayout(const float* __restrict__ src, uint16_t* __restrict__ dst) {
  __shared__ uint16_t lds[16][520];      // 1040B row stride (bank skew)
  const int lane = threadIdx.x & 63;
  const int wv = threadIdx.x >> 6;
  const size_t R0 = (size_t)blockIdx.x << 4;
  #pragma unroll
  for (int i = 0; i < 4; ++i) {
    const int r = (wv << 2) + i;         // local row 0..15
    const float4* s = (const float4*)(src + (R0 + r) * ND) + (lane << 1);
    float4 a = s[0], b = s[1];
    float ss = a.x*a.x + a.y*a.y + a.z*a.z + a.w*a.w
             + b.x*b.x + b.y*b.y + b.z*b.z + b.w*b.w;
    #pragma unroll
    for (int o = 32; o; o >>= 1) ss += __shfl_xor(ss, o);
    const float inv = 1.0f / fmaxf(sqrtf(ss), 1e-8f);
    uint4 o4;
    o4.x = pack2bf(a.x * inv, a.y * inv);
    o4.y = pack2bf(a.z * inv, a.w * inv);
    o4.z = pack2bf(b.x * inv, b.y * inv);
    o4.w = pack2bf(b.z * inv, b.w * inv);
    *(uint4*)(&lds[r][lane << 3]) = o4;  // row-major, byte off lane*16
  }
  __syncthreads();
  uint16_t* out = dst + ((size_t)blockIdx.x << 13);
  #pragma unroll
  for (int c = 0; c < 4; ++c) {
    const int idx = (c << 8) + threadIdx.x;        // 16B-unit index 0..1023
    const int kc = idx >> 6, g = (idx >> 4) & 3, rs = idx & 15;
    uint4 v = *(const uint4*)(&lds[rs][(kc << 5) + (g << 3)]);
    ((uint4*)out)[idx] = v;
  }
}

// ---------- kernel 2: exact fp32 target cosine t_b (unchanged) ----------
__global__ void target_cos_kernel(const float* __restrict__ x,
                                  const float* __restrict__ cls,
                                  const int* __restrict__ tgt,
                                  float* __restrict__ t) {
  const int b = blockIdx.x;
  const int row = tgt[b];
  const float2* xr = (const float2*)(x + (size_t)b * ND);
  const float2* cr = (const float2*)(cls + (size_t)row * ND);
  float2 xv = xr[threadIdx.x], cv = cr[threadIdx.x];
  float sx = xv.x * xv.x + xv.y * xv.y;
  float sc = cv.x * cv.x + cv.y * cv.y;
  float sd = xv.x * cv.x + xv.y * cv.y;
  #pragma unroll
  for (int o = 32; o; o >>= 1) {
    sx += __shfl_down(sx, o);
    sc += __shfl_down(sc, o);
    sd += __shfl_down(sd, o);
  }
  __shared__ float r[3][4];
  const int wv = threadIdx.x >> 6;
  if ((threadIdx.x & 63) == 0) { r[0][wv] = sx; r[1][wv] = sc; r[2][wv] = sd; }
  __syncthreads();
  if (threadIdx.x == 0) {
    float ax = r[0][0] + r[0][1] + r[0][2] + r[0][3];
    float ac = r[1][0] + r[1][1] + r[1][2] + r[1][3];
    float ad = r[2][0] + r[2][1] + r[2][2] + r[2][3];
    t[b] = ad / (fmaxf(sqrtf(ax), 1e-8f) * fmaxf(sqrtf(ac), 1e-8f));
  }
}

// ---------- kernel 3: LDS-staged MFMA GEMM, minimum-sync schedule ----------
// 512 thr = 8 waves (2M x 4N). Block tile 256x256, wave 128x64 = 8x4 of
// 16x16x32. BK=32 -> 16 K-tiles; 4 LDS buffers x 32KB, staging 3 tiles ahead
// via global_load_lds, counted vmcnt(8) steady state (never 0 in main loop).
// ONE barrier per K-tile (the only hazard points: 4-deep buffer wrap +
// staged-data visibility). Within a tile, each wave waits only its OWN
// ds_reads (lgkmcnt(0), split 8+4), so waves desync and one wave's MFMA
// cluster overlaps another's LDS drain — the overlap the lockstep version
// forbade. setprio(1) around MFMA arbitrates the role-split.
__device__ __forceinline__ void gload16(const char* g, char* l) {
  __builtin_amdgcn_global_load_lds(
      (__attribute__((address_space(1))) void*)(g),
      (__attribute__((address_space(3))) void*)(l), 16, 0, 0);
}
#define WAITVM(N)  asm volatile("s_waitcnt vmcnt(" #N ")" ::: "memory")
#define LGKM0()    asm volatile("s_waitcnt lgkmcnt(0)" ::: "memory")

__global__ __launch_bounds__(512, 2)
void hinge_gemm_pipe(const uint16_t* __restrict__ Wf,   // frag-layout classes
                     const uint16_t* __restrict__ Xf,   // frag-layout inputs
                     const float* __restrict__ t,       // [NB]
                     float* __restrict__ accum) {       // [64]
  const int id = blockIdx.x;
  // bijective XCD swizzle: grid = 49*32; same-mt blocks share id%8 -> same XCD
  const int mt = (id & 7) + ((id >> 5) << 3);   // 0..391
  const int nt = (id >> 3) & 3;                 // 0..3
  if (mt >= MTILES) return;

  __shared__ __align__(1024) char lds[131072];  // 4 bufs x (A 16KB + B 16KB)
  __shared__ float part[8];

  const int lane = threadIdx.x & 63;
  const int wv = threadIdx.x >> 6;
  const int wm = wv & 1;        // 128-row half of A
  const int wn = wv >> 1;       // 64-col quarter of B
  const int laneoff = lane << 4;
  const int aoff = wm << 13;                 // wm*8 slices * 1KB
  const int boff = (1 << 14) + (wn << 12);   // B region + wn*4 slices

  // per-lane global sources (kt=0) + wave-uniform LDS dst offsets.
  // wave wv stages slices wv*4 .. wv*4+3 (0..15 = A frags, 16..31 = B frags)
  const char* gsrc[4];
  int dsto[4];
  #pragma unroll
  for (int i = 0; i < 4; ++i) {
    const int sl = (wv << 2) + i;
    if (sl < 16) {
      gsrc[i] = (const char*)Wf + (((size_t)(mt * 16 + sl)) << 14) + laneoff;
      dsto[i] = sl << 10;
    } else {
      gsrc[i] = (const char*)Xf + (((size_t)(nt * 16 + (sl - 16))) << 14) + laneoff;
      dsto[i] = (1 << 14) + ((sl - 16) << 10);
    }
  }

  f32x4 acc[8][4];
  #pragma unroll
  for (int i = 0; i < 8; ++i)
    #pragma unroll
    for (int j = 0; j < 4; ++j)
      acc[i][j] = (f32x4){0.f, 0.f, 0.f, 0.f};

  bf16x8 a03[4], a47[4], bfr[4];

#define STAGE_H(T, H) {                                                    \
    char* lb_ = lds + (((T) & 3) << 15);                                   \
    gload16(gsrc[(H)*2]     + ((size_t)(T) << 10), lb_ + dsto[(H)*2]);     \
    gload16(gsrc[(H)*2 + 1] + ((size_t)(T) << 10), lb_ + dsto[(H)*2 + 1]); }

#define DSR_A03B(KT) {                                                     \
    const char* base_ = lds + (((KT) & 3) << 15);                          \
    _Pragma("unroll")                                                      \
    for (int i_ = 0; i_ < 4; ++i_)                                         \
      a03[i_] = *(const bf16x8*)(base_ + aoff + (i_ << 10) + laneoff);     \
    _Pragma("unroll")                                                      \
    for (int j_ = 0; j_ < 4; ++j_)                                         \
      bfr[j_] = *(const bf16x8*)(base_ + boff + (j_ << 10) + laneoff); }

#define DSR_A47(KT) {                                                      \
    const char* base_ = lds + (((KT) & 3) << 15);                          \
    _Pragma("unroll")                                                      \
    for (int i_ = 0; i_ < 4; ++i_)                                         \
      a47[i_] = *(const bf16x8*)(base_ + aoff + ((i_ + 4) << 10) + laneoff); }

#define MFMA_LO() {                                                        \
    __builtin_amdgcn_s_setprio(1);                                         \
    _Pragma("unroll")                                                      \
    for (int m_ = 0; m_ < 4; ++m_)                                         \
      _Pragma("unroll")                                                    \
      for (int j_ = 0; j_ < 4; ++j_)                                       \
        acc[m_][j_] = __builtin_amdgcn_mfma_f32_16x16x32_bf16(             \
            a03[m_], bfr[j_], acc[m_][j_], 0, 0, 0);                       \
    __builtin_amdgcn_s_setprio(0); }

#define MFMA_HI() {                                                        \
    __builtin_amdgcn_s_setprio(1);                                         \
    _Pragma("unroll")                                                      \
    for (int m_ = 0; m_ < 4; ++m_)                                         \
      _Pragma("unroll")                                                    \
      for (int j_ = 0; j_ < 4; ++j_)                                       \
        acc[m_ + 4][j_] = __builtin_amdgcn_mfma_f32_16x16x32_bf16(         \
            a47[m_], bfr[j_], acc[m_ + 4][j_], 0, 0, 0);                   \
    __builtin_amdgcn_s_setprio(0); }

  // prologue: 3 K-tiles in flight; publish tile 0 (own loads via vmcnt, all
  // waves via barrier)
  STAGE_H(0, 0); STAGE_H(0, 1);
  STAGE_H(1, 0); STAGE_H(1, 1);
  STAGE_H(2, 0); STAGE_H(2, 1);
  WAITVM(8);                         // STAGE(0) landed (8 newer outstanding)
  __builtin_amdgcn_s_barrier();

  #pragma unroll 1
  for (int kt = 0; kt < 13; ++kt) {
    // sub-phase 1: stage half, read 8 frags, wait own reads only, 16 MFMA
    STAGE_H(kt + 3, 0);
    DSR_A03B(kt);
    LGKM0();
    __builtin_amdgcn_sched_barrier(0);
    MFMA_LO();
    // sub-phase 2: stage half, read 4 frags, counted vmcnt, 16 MFMA
    STAGE_H(kt + 3, 1);
    DSR_A47(kt);
    WAITVM(8);                       // STAGE(kt+1) landed (kt+2, kt+3 in flight)
    LGKM0();
    __builtin_amdgcn_sched_barrier(0);
    MFMA_HI();
    // single hazard barrier: publishes STAGE(kt+1) to all waves AND
    // guarantees all waves' reads of tile kt are done before anyone
    // overwrites buf[(kt+4)&3] = buf[kt&3] next iteration.
    __builtin_amdgcn_s_barrier();
  }
  // tail tiles 13..15: no staging, drain vmcnt 4 -> 0
  DSR_A03B(13); LGKM0(); __builtin_amdgcn_sched_barrier(0); MFMA_LO();
  DSR_A47(13);  WAITVM(4); LGKM0(); __builtin_amdgcn_sched_barrier(0); MFMA_HI();
  __builtin_amdgcn_s_barrier();
  DSR_A03B(14); LGKM0(); __builtin_amdgcn_sched_barrier(0); MFMA_LO();
  DSR_A47(14);  WAITVM(0); LGKM0(); __builtin_amdgcn_sched_barrier(0); MFMA_HI();
  __builtin_amdgcn_s_barrier();
  DSR_A03B(15); LGKM0(); __builtin_amdgcn_sched_barrier(0); MFMA_LO();
  DSR_A47(15);  LGKM0(); __builtin_amdgcn_sched_barrier(0); MFMA_HI();

  // ---- epilogue: hinge + block reduction ----
  // C/D: col(N) = lane&15, row(M) = (lane>>4)*4 + reg
  const int m0 = mt << 8, n0 = nt << 8;
  const int lr = lane & 15;
  const int rb4 = (lane >> 4) << 2;
  float local = 0.f;
  #pragma unroll
  for (int j = 0; j < 4; ++j) {
    const int n = n0 + (wn << 6) + (j << 4) + lr;
    const float base = MARGINF - t[n];
    #pragma unroll
    for (int ms = 0; ms < 8; ++ms) {
      const int mr = m0 + (wm << 7) + (ms << 4) + rb4;
      f32x4 v = acc[ms][j];
      #pragma unroll
      for (int rr = 0; rr < 4; ++rr)
        if (mr + rr < NC) local += fmaxf(base + v[rr], 0.f);
    }
  }
  #pragma unroll
  for (int o = 32; o; o >>= 1) local += __shfl_down(local, o);
  if (lane == 0) part[wv] = local;
  __syncthreads();
  if (threadIdx.x == 0) {
    float s = 0.f;
    #pragma unroll
    for (int i = 0; i < 8; ++i) s += part[i];
    atomicAdd(&accum[id & 63], s);
  }
#undef STAGE_H
#undef DSR_A03B
#undef DSR_A47
#undef MFMA_LO
#undef MFMA_HI
}

// ---------- kernel 4: finalize ----------
__global__ void finalize_kernel(const float* __restrict__ accum, float* __restrict__ out) {
  float s = 0.f;
  #pragma unroll
  for (int i = 0; i < 64; ++i) s += accum[i];
  out[0] = s * (1.0f / (float)NB) - MARGINF;
}

// ---------- workspace layout ----------
//   Wf   : 0            .. 102,400,000   (6250 frag-tiles x 16KB)
//   Xf   : 102,400,000  .. 103,448,576   (64 frag-tiles x 16KB)
//   t    : 103,448,576  .. 103,452,672   (NB fp32)
//   acc  : 103,452,672  .. +256          (64 fp32)
// NOTE: GEMM mt=390 reads frag-tiles 6250..6255 (bytes .. 102,498,304) which
// overrun Wf into Xf — allocated, finite bf16 garbage, masked by mr<NC.
#define WS_WF 0
#define WS_XF 102400000ull
#define WS_T  103448576ull
#define WS_ACC 103452672ull

extern "C" void kernel_launch(void* const* d_in, const int* in_sizes, int n_in,
                              void* d_out, int out_size, void* d_ws, size_t ws_size,
                              hipStream_t stream) {
  const float* inputs = (const float*)d_in[0];
  const float* cls    = (const float*)d_in[1];
  const int*   tgt    = (const int*)d_in[2];
  float* out = (float*)d_out;
  char* ws = (char*)d_ws;
  uint16_t* Wf = (uint16_t*)(ws + WS_WF);
  uint16_t* Xf = (uint16_t*)(ws + WS_XF);
  float* t     = (float*)(ws + WS_T);
  float* accum = (float*)(ws + WS_ACC);

  (void)hipMemsetAsync(accum, 0, 64 * sizeof(float), stream);
  normalize_relayout<<<64, 256, 0, stream>>>(inputs, Xf);     // 1024 rows
  normalize_relayout<<<6250, 256, 0, stream>>>(cls, Wf);      // 100000 rows
  target_cos_kernel<<<NB, 256, 0, stream>>>(inputs, cls, tgt, t);
  // 49*32 = 1568 blocks cover 392 mt x 4 nt; mt guarded at 391
  hinge_gemm_pipe<<<1568, 512, 0, stream>>>(Wf, Xf, t, accum);
  finalize_kernel<<<1, 1, 0, stream>>>(accum, out);
}

// Round 3
// 418.266 us; speedup vs baseline: 1.0676x; 1.0676x over previous
//
#include <hip/hip_runtime.h>
#include <stdint.h>

#define NB 1024
#define ND 512
#define NC 100000
#define MTILES 391       // ceil(NC/256)
#define MARGINF 0.1f

using bf16x8 = __attribute__((ext_vector_type(8))) short;
using f32x4  = __attribute__((ext_vector_type(4))) float;

// ---------- helpers ----------
__device__ __forceinline__ uint32_t f2bf(float f) {
  uint32_t u = __float_as_uint(f);
  return (u + 0x7fffu + ((u >> 16) & 1u)) >> 16;
}
__device__ __forceinline__ uint32_t pack2bf(float x, float y) {
  return f2bf(x) | (f2bf(y) << 16);
}

// ---------- kernel 1: normalize fp32 rows -> bf16 in MFMA-FRAGMENT layout ----
// Block = 256 thr, 16 rows. Output: one 16KB "frag-tile" per block; fragment
// kc (1KB) covers k in [kc*32, kc*32+32); 16B unit u = g*16 + rs holds row rs,
// k = kc*32 + g*8 .. +8 — exactly the 16x16x32 MFMA operand order, so a lane's
// fragment is at base + lane*16.
__global__ __launch_bounds__(256)
void normalize_relayout(const float* __restrict__ src, uint16_t* __restrict__ dst) {
  __shared__ uint16_t lds[16][520];      // 1040B row stride (bank skew)
  const int lane = threadIdx.x & 63;
  const int wv = threadIdx.x >> 6;
  const size_t R0 = (size_t)blockIdx.x << 4;
  #pragma unroll
  for (int i = 0; i < 4; ++i) {
    const int r = (wv << 2) + i;         // local row 0..15
    const float4* s = (const float4*)(src + (R0 + r) * ND) + (lane << 1);
    float4 a = s[0], b = s[1];
    float ss = a.x*a.x + a.y*a.y + a.z*a.z + a.w*a.w
             + b.x*b.x + b.y*b.y + b.z*b.z + b.w*b.w;
    #pragma unroll
    for (int o = 32; o; o >>= 1) ss += __shfl_xor(ss, o);
    const float inv = 1.0f / fmaxf(sqrtf(ss), 1e-8f);
    uint4 o4;
    o4.x = pack2bf(a.x * inv, a.y * inv);
    o4.y = pack2bf(a.z * inv, a.w * inv);
    o4.z = pack2bf(b.x * inv, b.y * inv);
    o4.w = pack2bf(b.z * inv, b.w * inv);
    *(uint4*)(&lds[r][lane << 3]) = o4;  // row-major, byte off lane*16
  }
  __syncthreads();
  uint16_t* out = dst + ((size_t)blockIdx.x << 13);
  #pragma unroll
  for (int c = 0; c < 4; ++c) {
    const int idx = (c << 8) + threadIdx.x;        // 16B-unit index 0..1023
    const int kc = idx >> 6, g = (idx >> 4) & 3, rs = idx & 15;
    uint4 v = *(const uint4*)(&lds[rs][(kc << 5) + (g << 3)]);
    ((uint4*)out)[idx] = v;
  }
}

// ---------- kernel 2: exact fp32 target cosine t_b (unchanged) ----------
__global__ void target_cos_kernel(const float* __restrict__ x,
                                  const float* __restrict__ cls,
                                  const int* __restrict__ tgt,
                                  float* __restrict__ t) {
  const int b = blockIdx.x;
  const int row = tgt[b];
  const float2* xr = (const float2*)(x + (size_t)b * ND);
  const float2* cr = (const float2*)(cls + (size_t)row * ND);
  float2 xv = xr[threadIdx.x], cv = cr[threadIdx.x];
  float sx = xv.x * xv.x + xv.y * xv.y;
  float sc = cv.x * cv.x + cv.y * cv.y;
  float sd = xv.x * cv.x + xv.y * cv.y;
  #pragma unroll
  for (int o = 32; o; o >>= 1) {
    sx += __shfl_down(sx, o);
    sc += __shfl_down(sc, o);
    sd += __shfl_down(sd, o);
  }
  __shared__ float r[3][4];
  const int wv = threadIdx.x >> 6;
  if ((threadIdx.x & 63) == 0) { r[0][wv] = sx; r[1][wv] = sc; r[2][wv] = sd; }
  __syncthreads();
  if (threadIdx.x == 0) {
    float ax = r[0][0] + r[0][1] + r[0][2] + r[0][3];
    float ac = r[1][0] + r[1][1] + r[1][2] + r[1][3];
    float ad = r[2][0] + r[2][1] + r[2][2] + r[2][3];
    t[b] = ad / (fmaxf(sqrtf(ax), 1e-8f) * fmaxf(sqrtf(ac), 1e-8f));
  }
}

// ---------- kernel 3: MFMA GEMM, faithful 8-phase-template schedule ----------
// 512 thr = 8 waves (2M x 4N). Block tile 256x256, wave 128x64 = 8x4 of
// 16x16x32. BK=32 -> 16 K-tiles; 4-deep LDS ring (4 x 32KB), staging 3 tiles
// ahead via global_load_lds. Per tile, TWO template phases (16 MFMA each):
//   { ds_reads ; 2 gload_lds ; [vmcnt(8) in hi] ; s_barrier ;
//     lgkmcnt(0) ; sched_barrier(0) ; setprio(1) 16xMFMA setprio(0) ;
//     s_barrier }
// ds_reads are issued BEFORE the barrier so their latency drains during the
// barrier wait; lgkmcnt(0) comes AFTER it (m201 template). vmcnt is counted
// (8 steady, 4->0 tail), never drained in the main loop. Frag-native layout
// gives linear gload_lds dests and conflict-free lane*16 ds_read_b128.
__device__ __forceinline__ void gload16(const char* g, char* l) {
  __builtin_amdgcn_global_load_lds(
      (__attribute__((address_space(1))) void*)(g),
      (__attribute__((address_space(3))) void*)(l), 16, 0, 0);
}
#define WAITVM(N)  asm volatile("s_waitcnt vmcnt(" #N ")" ::: "memory")
#define LGKM0()    asm volatile("s_waitcnt lgkmcnt(0)" ::: "memory")

__global__ __launch_bounds__(512, 2)
void hinge_gemm_pipe(const uint16_t* __restrict__ Wf,   // frag-layout classes
                     const uint16_t* __restrict__ Xf,   // frag-layout inputs
                     const float* __restrict__ t,       // [NB]
                     float* __restrict__ accum) {       // [64]
  const int id = blockIdx.x;
  // bijective XCD swizzle: grid = 49*32; same-mt blocks share id%8 -> same XCD
  const int mt = (id & 7) + ((id >> 5) << 3);   // 0..391
  const int nt = (id >> 3) & 3;                 // 0..3
  if (mt >= MTILES) return;

  __shared__ __align__(1024) char lds[131072];  // 4 bufs x (A 16KB + B 16KB)
  __shared__ float part[8];

  const int lane = threadIdx.x & 63;
  const int wv = threadIdx.x >> 6;
  const int wm = wv & 1;        // 128-row half of A
  const int wn = wv >> 1;       // 64-col quarter of B
  const int laneoff = lane << 4;
  const int aoff = wm << 13;                 // wm*8 slices * 1KB
  const int boff = (1 << 14) + (wn << 12);   // B region + wn*4 slices

  // per-lane global sources (kt=0) + wave-uniform LDS dst offsets.
  // wave wv stages slices wv*4 .. wv*4+3 (0..15 = A frags, 16..31 = B frags)
  const char* gsrc[4];
  int dsto[4];
  #pragma unroll
  for (int i = 0; i < 4; ++i) {
    const int sl = (wv << 2) + i;
    if (sl < 16) {
      gsrc[i] = (const char*)Wf + (((size_t)(mt * 16 + sl)) << 14) + laneoff;
      dsto[i] = sl << 10;
    } else {
      gsrc[i] = (const char*)Xf + (((size_t)(nt * 16 + (sl - 16))) << 14) + laneoff;
      dsto[i] = (1 << 14) + ((sl - 16) << 10);
    }
  }

  f32x4 acc[8][4];
  #pragma unroll
  for (int i = 0; i < 8; ++i)
    #pragma unroll
    for (int j = 0; j < 4; ++j)
      acc[i][j] = (f32x4){0.f, 0.f, 0.f, 0.f};

  bf16x8 a03[4], a47[4], bfr[4];

#define STAGE_H(T, H) {                                                    \
    char* lb_ = lds + (((T) & 3) << 15);                                   \
    gload16(gsrc[(H)*2]     + ((size_t)(T) << 10), lb_ + dsto[(H)*2]);     \
    gload16(gsrc[(H)*2 + 1] + ((size_t)(T) << 10), lb_ + dsto[(H)*2 + 1]); }

#define DSR_A03B(KT) {                                                     \
    const char* base_ = lds + (((KT) & 3) << 15);                          \
    _Pragma("unroll")                                                      \
    for (int i_ = 0; i_ < 4; ++i_)                                         \
      a03[i_] = *(const bf16x8*)(base_ + aoff + (i_ << 10) + laneoff);     \
    _Pragma("unroll")                                                      \
    for (int j_ = 0; j_ < 4; ++j_)                                         \
      bfr[j_] = *(const bf16x8*)(base_ + boff + (j_ << 10) + laneoff); }

#define DSR_A47(KT) {                                                      \
    const char* base_ = lds + (((KT) & 3) << 15);                          \
    _Pragma("unroll")                                                      \
    for (int i_ = 0; i_ < 4; ++i_)                                         \
      a47[i_] = *(const bf16x8*)(base_ + aoff + ((i_ + 4) << 10) + laneoff); }

#define MFMA_LO() {                                                        \
    __builtin_amdgcn_s_setprio(1);                                         \
    _Pragma("unroll")                                                      \
    for (int m_ = 0; m_ < 4; ++m_)                                         \
      _Pragma("unroll")                                                    \
      for (int j_ = 0; j_ < 4; ++j_)                                       \
        acc[m_][j_] = __builtin_amdgcn_mfma_f32_16x16x32_bf16(             \
            a03[m_], bfr[j_], acc[m_][j_], 0, 0, 0);                       \
    __builtin_amdgcn_s_setprio(0); }

#define MFMA_HI() {                                                        \
    __builtin_amdgcn_s_setprio(1);                                         \
    _Pragma("unroll")                                                      \
    for (int m_ = 0; m_ < 4; ++m_)                                         \
      _Pragma("unroll")                                                    \
      for (int j_ = 0; j_ < 4; ++j_)                                       \
        acc[m_ + 4][j_] = __builtin_amdgcn_mfma_f32_16x16x32_bf16(         \
            a47[m_], bfr[j_], acc[m_ + 4][j_], 0, 0, 0);                   \
    __builtin_amdgcn_s_setprio(0); }

// template phase pair for one K-tile. LO: 8 ds_read + 2 gload; HI: 4 ds_read
// + 2 gload + counted vmcnt. Barrier BEFORE lgkmcnt(0): read latency drains
// during the barrier wait; sched_barrier(0) pins MFMA after the wait (rule 18).
#define PHASE_LO(KT, DOSTAGE) {                                            \
    DSR_A03B(KT);                                                          \
    if (DOSTAGE) STAGE_H((KT) + 3, 0);                                     \
    __builtin_amdgcn_s_barrier();                                          \
    LGKM0();                                                               \
    __builtin_amdgcn_sched_barrier(0);                                     \
    MFMA_LO();                                                             \
    __builtin_amdgcn_s_barrier(); }

#define PHASE_HI_BODY(KT) {                                                \
    __builtin_amdgcn_s_barrier();                                          \
    LGKM0();                                                               \
    __builtin_amdgcn_sched_barrier(0);                                     \
    MFMA_HI();                                                             \
    __builtin_amdgcn_s_barrier(); }

  // prologue: 3 K-tiles in flight; publish tile 0
  STAGE_H(0, 0); STAGE_H(0, 1);
  STAGE_H(1, 0); STAGE_H(1, 1);
  STAGE_H(2, 0); STAGE_H(2, 1);
  WAITVM(8);                         // tile 0's 4 loads landed (8 newer out)
  __builtin_amdgcn_s_barrier();

  #pragma unroll 1
  for (int kt = 0; kt < 13; ++kt) {
    PHASE_LO(kt, 1);
    DSR_A47(kt);
    STAGE_H(kt + 3, 1);
    WAITVM(8);                       // tile kt+1's loads landed (kt+2,kt+3 out)
    PHASE_HI_BODY(kt);
  }
  // tail tiles 13..15: no staging; drain vmcnt 4 -> 0
  PHASE_LO(13, 0);
  DSR_A47(13); WAITVM(4); PHASE_HI_BODY(13);
  PHASE_LO(14, 0);
  DSR_A47(14); WAITVM(0); PHASE_HI_BODY(14);
  PHASE_LO(15, 0);
  DSR_A47(15); PHASE_HI_BODY(15);

  // ---- epilogue: hinge + block reduction ----
  // C/D: col(N) = lane&15, row(M) = (lane>>4)*4 + reg
  const int m0 = mt << 8, n0 = nt << 8;
  const int lr = lane & 15;
  const int rb4 = (lane >> 4) << 2;
  float local = 0.f;
  #pragma unroll
  for (int j = 0; j < 4; ++j) {
    const int n = n0 + (wn << 6) + (j << 4) + lr;
    const float base = MARGINF - t[n];
    #pragma unroll
    for (int ms = 0; ms < 8; ++ms) {
      const int mr = m0 + (wm << 7) + (ms << 4) + rb4;
      f32x4 v = acc[ms][j];
      #pragma unroll
      for (int rr = 0; rr < 4; ++rr)
        if (mr + rr < NC) local += fmaxf(base + v[rr], 0.f);
    }
  }
  #pragma unroll
  for (int o = 32; o; o >>= 1) local += __shfl_down(local, o);
  if (lane == 0) part[wv] = local;
  __syncthreads();
  if (threadIdx.x == 0) {
    float s = 0.f;
    #pragma unroll
    for (int i = 0; i < 8; ++i) s += part[i];
    atomicAdd(&accum[id & 63], s);
  }
#undef STAGE_H
#undef DSR_A03B
#undef DSR_A47
#undef MFMA_LO
#undef MFMA_HI
#undef PHASE_LO
#undef PHASE_HI_BODY
}

// ---------- kernel 4: finalize ----------
__global__ void finalize_kernel(const float* __restrict__ accum, float* __restrict__ out) {
  float s = 0.f;
  #pragma unroll
  for (int i = 0; i < 64; ++i) s += accum[i];
  out[0] = s * (1.0f / (float)NB) - MARGINF;
}

// ---------- workspace layout ----------
//   Wf   : 0            .. 102,400,000   (6250 frag-tiles x 16KB)
//   Xf   : 102,400,000  .. 103,448,576   (64 frag-tiles x 16KB)
//   t    : 103,448,576  .. 103,452,672   (NB fp32)
//   acc  : 103,452,672  .. +256          (64 fp32)
// NOTE: GEMM mt=390 reads frag-tiles 6250..6255 (bytes .. 102,498,304) which
// overrun Wf into Xf — allocated, finite bf16 garbage, masked by mr<NC.
#define WS_WF 0
#define WS_XF 102400000ull
#define WS_T  103448576ull
#define WS_ACC 103452672ull

extern "C" void kernel_launch(void* const* d_in, const int* in_sizes, int n_in,
                              void* d_out, int out_size, void* d_ws, size_t ws_size,
                              hipStream_t stream) {
  const float* inputs = (const float*)d_in[0];
  const float* cls    = (const float*)d_in[1];
  const int*   tgt    = (const int*)d_in[2];
  float* out = (float*)d_out;
  char* ws = (char*)d_ws;
  uint16_t* Wf = (uint16_t*)(ws + WS_WF);
  uint16_t* Xf = (uint16_t*)(ws + WS_XF);
  float* t     = (float*)(ws + WS_T);
  float* accum = (float*)(ws + WS_ACC);

  (void)hipMemsetAsync(accum, 0, 64 * sizeof(float), stream);
  normalize_relayout<<<64, 256, 0, stream>>>(inputs, Xf);     // 1024 rows
  normalize_relayout<<<6250, 256, 0, stream>>>(cls, Wf);      // 100000 rows
  target_cos_kernel<<<NB, 256, 0, stream>>>(inputs, cls, tgt, t);
  // 49*32 = 1568 blocks cover 392 mt x 4 nt; mt guarded at 391
  hinge_gemm_pipe<<<1568, 512, 0, stream>>>(Wf, Xf, t, accum);
  finalize_kernel<<<1, 1, 0, stream>>>(accum, out);
}